// Round 10
// baseline (130.880 us; speedup 1.0000x reference)
//
#include <hip/hip_runtime.h>

#define HH 1024
#define WW 1024
#define BB 8
#define WORDS_X 16             /* 64-px bit-words per row */

typedef unsigned long long u64;

// ---------------------------------------------------------------------------
// Kernel 1: pack target (int32 0/1) into a bit image. Pure stream: per wave,
// 8 independent coalesced 256B loads -> 8 ballots -> one 64B store.
// Also zeroes d_out[0] every call (harness re-poisons it to 0xAA); the
// kernel boundary before ls_loss makes the zero coherent for the atomics.
// ---------------------------------------------------------------------------
__global__ __launch_bounds__(256) void ls_pack(const int* __restrict__ tgt,
                                               u64* __restrict__ bits,
                                               float* __restrict__ out) {
    if (blockIdx.x == 0 && threadIdx.x == 0) out[0] = 0.0f;

    const int lane = threadIdx.x & 63;
    const size_t wv = ((size_t)blockIdx.x * 256 + threadIdx.x) >> 6;
    const size_t wbase = wv * 8;                 // first of 8 words (512 px)
    const int* p = tgt + wbase * 64 + lane;

    int v[8];
#pragma unroll
    for (int j = 0; j < 8; ++j) v[j] = p[j * 64];

    u64 mine = 0;
#pragma unroll
    for (int j = 0; j < 8; ++j) {
        u64 m = __ballot(v[j] != 0);
        if (lane == j) mine = m;
    }
    if (lane < 8) bits[wbase + lane] = mine;
}

// ---------------------------------------------------------------------------
// Kernel 2: fused edge-from-bits + loss. 64x64 tile per block.
//   t_c=0: edge <=> OR of 11x11 window ; t_c=1: edge <=> !(AND of window)
// (exactly 121*t_c != window_sum with zero padding: OOB rows/words = 0.)
// Block result accumulated into d_out[0] via ONE native f32 atomicAdd,
// pre-scaled by -1/N. No fences (r7/r8: per-block __threadfence = ~88us
// L2-writeback storm). No final kernel needed.
// ---------------------------------------------------------------------------
__global__ __launch_bounds__(256) void ls_loss(const float* __restrict__ x,
                                               const u64* __restrict__ bits,
                                               float* __restrict__ out) {
    __shared__ u64 s_w[74][3];
    __shared__ u64 s_oh[74], s_ah[74], s_e[64];
    __shared__ float s_red[4];

    const int tid = threadIdx.x;
    const int b  = blockIdx.z;
    const int ty = blockIdx.y * 64;
    const int wx = blockIdx.x;               // word index == tile col block

    // ---- Stage 74 rows x 3 bit-words (one 8B load per thread, OOB->0) ----
    if (tid < 222) {
        int r = tid / 3, k = tid - 3 * r;
        int gy = ty - 5 + r;
        int wi = wx - 1 + k;
        u64 v = 0;
        if ((unsigned)gy < HH && (unsigned)wi < WORDS_X)
            v = bits[((size_t)(b << 10) + gy) * WORDS_X + wi];
        s_w[r][k] = v;
    }

    // ---- x loads: 16 px/thread (one row, cols c0..c0+15) ----
    const int row = tid >> 2;
    const int c0  = (tid & 3) << 4;
    const float* x0p = x + ((size_t)b * 2 + 0) * HH * WW
                         + (size_t)(ty + row) * WW + (wx << 6) + c0;
    const float* x1p = x0p + (size_t)HH * WW;
    float4 xv0[4], xv1[4];
#pragma unroll
    for (int q = 0; q < 4; ++q) xv0[q] = ((const float4*)x0p)[q];
#pragma unroll
    for (int q = 0; q < 4; ++q) xv1[q] = ((const float4*)x1p)[q];

    __syncthreads();

    // ---- Horizontal 11-window OR/AND (funnel shift over 192 bits) ----
    if (tid < 74) {
        u64 wl = s_w[tid][0], wm = s_w[tid][1], wr = s_w[tid][2];
        u64 oh = wm, ah = wm;
#pragma unroll
        for (int d = 1; d <= 5; ++d) {
            u64 vr = (wm >> d) | (wr << (64 - d));
            u64 vl = (wm << d) | (wl >> (64 - d));
            oh |= vr | vl;
            ah &= vr & vl;
        }
        s_oh[tid] = oh;
        s_ah[tid] = ah;
    }
    __syncthreads();

    // ---- Vertical 11-window; per-row edge word ----
    if (tid < 64) {
        u64 ov = 0, av = ~0ULL;
#pragma unroll
        for (int k = 0; k < 11; ++k) { ov |= s_oh[tid + k]; av &= s_ah[tid + k]; }
        u64 tc = s_w[tid + 5][1];
        s_e[tid] = (ov & ~tc) | (~av & tc);
    }
    __syncthreads();

    // ---- Loss: 16 px/thread ----
    unsigned int e16 = (unsigned int)(s_e[row] >> c0) & 0xffffu;
    unsigned int t16 = (unsigned int)(s_w[row + 5][1] >> c0) & 0xffffu;

    const float* f0 = (const float*)xv0;
    const float* f1 = (const float*)xv1;
    float acc = 0.f;
#pragma unroll
    for (int j = 0; j < 16; ++j) {
        int t = (t16 >> j) & 1;
        int e = (e16 >> j) & 1;
        float v0 = f0[j], v1 = f1[j];
        float m   = fmaxf(v0, v1);
        float lse = m + __logf(1.0f + __expf(-fabsf(v0 - v1)));
        float lp0 = v0 - lse, lp1 = v1 - lse;
        float lpt = t ? lp1 : lp0;
        float lpo = t ? lp0 : lp1;
        acc += e ? (0.95f * lpt + 0.1f * lpo) : lpt;
    }

#pragma unroll
    for (int off = 32; off > 0; off >>= 1) acc += __shfl_down(acc, off, 64);
    if ((tid & 63) == 0) s_red[tid >> 6] = acc;
    __syncthreads();
    if (tid == 0) {
        float bs = s_red[0] + s_red[1] + s_red[2] + s_red[3];
        // One native f32 atomic per block; pre-scaled so out holds -mean.
        atomicAdd(out, bs * (-1.0f / (8.0f * 1024.0f * 1024.0f)));
    }
}

extern "C" void kernel_launch(void* const* d_in, const int* in_sizes, int n_in,
                              void* d_out, int out_size, void* d_ws, size_t ws_size,
                              hipStream_t stream) {
    const float* x  = (const float*)d_in[0];
    const int* tgt  = (const int*)d_in[1];

    // ws: [bit image @16KB, 1MB]
    u64* bits = (u64*)((char*)d_ws + (16 << 10));
    float* out = (float*)d_out;

    hipLaunchKernelGGL(ls_pack, dim3(4096), dim3(256), 0, stream, tgt, bits, out);
    hipLaunchKernelGGL(ls_loss, dim3(16, 16, 8), dim3(256), 0, stream, x, bits, out);
}

// Round 11
// 117.994 us; speedup vs baseline: 1.1092x; 1.1092x over previous
//
#include <hip/hip_runtime.h>

#define HH 1024
#define WW 1024
#define BB 8
#define WORDS_X 16             /* 64-px bit-words per row */
#define NPART 2048

typedef unsigned long long u64;

// ---------------------------------------------------------------------------
// Kernel 1: pack target (int32 0/1) into a bit image. Pure stream: per wave,
// 8 independent coalesced 256B loads -> 8 ballots -> one 64B store.
// ---------------------------------------------------------------------------
__global__ __launch_bounds__(256) void ls_pack(const int* __restrict__ tgt,
                                               u64* __restrict__ bits) {
    const int lane = threadIdx.x & 63;
    const size_t wv = ((size_t)blockIdx.x * 256 + threadIdx.x) >> 6;
    const size_t wbase = wv * 8;                 // first of 8 words (512 px)
    const int* p = tgt + wbase * 64 + lane;

    int v[8];
#pragma unroll
    for (int j = 0; j < 8; ++j) v[j] = p[j * 64];

    u64 mine = 0;
#pragma unroll
    for (int j = 0; j < 8; ++j) {
        u64 m = __ballot(v[j] != 0);
        if (lane == j) mine = m;
    }
    if (lane < 8) bits[wbase + lane] = mine;
}

// ---------------------------------------------------------------------------
// Kernel 2: fused edge-from-bits + loss. 64x64 tile per block.
//   t_c=0: edge <=> OR of 11x11 window ; t_c=1: edge <=> !(AND of window)
// (exactly 121*t_c != window_sum with zero padding: OOB rows/words = 0.)
// NO device fences / cross-block atomics on the hot path (r7/r8: per-block
// __threadfence = ~88us L2-writeback storm; r10: contended f32 atomic =
// +12.7us tail). Coherence via kernel boundaries only.
// ---------------------------------------------------------------------------
__global__ __launch_bounds__(256) void ls_loss(const float* __restrict__ x,
                                               const u64* __restrict__ bits,
                                               float* __restrict__ partial) {
    __shared__ u64 s_w[74][3];
    __shared__ u64 s_oh[74], s_ah[74], s_e[64];
    __shared__ float s_red[4];

    const int tid = threadIdx.x;
    const int b  = blockIdx.z;
    const int ty = blockIdx.y * 64;
    const int wx = blockIdx.x;               // word index == tile col block

    // ---- Stage 74 rows x 3 bit-words (one 8B load per thread, OOB->0) ----
    if (tid < 222) {
        int r = tid / 3, k = tid - 3 * r;
        int gy = ty - 5 + r;
        int wi = wx - 1 + k;
        u64 v = 0;
        if ((unsigned)gy < HH && (unsigned)wi < WORDS_X)
            v = bits[((size_t)(b << 10) + gy) * WORDS_X + wi];
        s_w[r][k] = v;
    }

    // ---- x loads: 16 px/thread (one row, cols c0..c0+15); compiler may
    // schedule these freely — 8 blocks/CU hides the latency. ----
    const int row = tid >> 2;
    const int c0  = (tid & 3) << 4;
    const float* x0p = x + ((size_t)b * 2 + 0) * HH * WW
                         + (size_t)(ty + row) * WW + (wx << 6) + c0;
    const float* x1p = x0p + (size_t)HH * WW;
    float4 xv0[4], xv1[4];
#pragma unroll
    for (int q = 0; q < 4; ++q) xv0[q] = ((const float4*)x0p)[q];
#pragma unroll
    for (int q = 0; q < 4; ++q) xv1[q] = ((const float4*)x1p)[q];

    __syncthreads();

    // ---- Horizontal 11-window OR/AND (funnel shift over 192 bits) ----
    if (tid < 74) {
        u64 wl = s_w[tid][0], wm = s_w[tid][1], wr = s_w[tid][2];
        u64 oh = wm, ah = wm;
#pragma unroll
        for (int d = 1; d <= 5; ++d) {
            u64 vr = (wm >> d) | (wr << (64 - d));
            u64 vl = (wm << d) | (wl >> (64 - d));
            oh |= vr | vl;
            ah &= vr & vl;
        }
        s_oh[tid] = oh;
        s_ah[tid] = ah;
    }
    __syncthreads();

    // ---- Vertical 11-window; per-row edge word ----
    if (tid < 64) {
        u64 ov = 0, av = ~0ULL;
#pragma unroll
        for (int k = 0; k < 11; ++k) { ov |= s_oh[tid + k]; av &= s_ah[tid + k]; }
        u64 tc = s_w[tid + 5][1];
        s_e[tid] = (ov & ~tc) | (~av & tc);
    }
    __syncthreads();

    // ---- Loss: 16 px/thread ----
    unsigned int e16 = (unsigned int)(s_e[row] >> c0) & 0xffffu;
    unsigned int t16 = (unsigned int)(s_w[row + 5][1] >> c0) & 0xffffu;

    const float* f0 = (const float*)xv0;
    const float* f1 = (const float*)xv1;
    float acc = 0.f;
#pragma unroll
    for (int j = 0; j < 16; ++j) {
        int t = (t16 >> j) & 1;
        int e = (e16 >> j) & 1;
        float v0 = f0[j], v1 = f1[j];
        float m   = fmaxf(v0, v1);
        float lse = m + __logf(1.0f + __expf(-fabsf(v0 - v1)));
        float lp0 = v0 - lse, lp1 = v1 - lse;
        float lpt = t ? lp1 : lp0;
        float lpo = t ? lp0 : lp1;
        acc += e ? (0.95f * lpt + 0.1f * lpo) : lpt;
    }

#pragma unroll
    for (int off = 32; off > 0; off >>= 1) acc += __shfl_down(acc, off, 64);
    if ((tid & 63) == 0) s_red[tid >> 6] = acc;
    __syncthreads();
    if (tid == 0) {
        int bid = (blockIdx.z * gridDim.y + blockIdx.y) * gridDim.x + blockIdx.x;
        partial[bid] = s_red[0] + s_red[1] + s_red[2] + s_red[3];
    }
}

__global__ __launch_bounds__(1024) void ls_final(const float* __restrict__ partial,
                                                 float* __restrict__ out) {
    __shared__ double s_red[16];
    const int tid = threadIdx.x;
    double s = (double)partial[tid] + (double)partial[tid + 1024];
#pragma unroll
    for (int off = 32; off > 0; off >>= 1) s += __shfl_down(s, off, 64);
    if ((tid & 63) == 0) s_red[tid >> 6] = s;
    __syncthreads();
    if (tid == 0) {
        double total = 0.0;
#pragma unroll
        for (int i = 0; i < 16; ++i) total += s_red[i];
        out[0] = (float)(-total * (1.0 / (8.0 * 1024.0 * 1024.0)));
    }
}

extern "C" void kernel_launch(void* const* d_in, const int* in_sizes, int n_in,
                              void* d_out, int out_size, void* d_ws, size_t ws_size,
                              hipStream_t stream) {
    const float* x  = (const float*)d_in[0];
    const int* tgt  = (const int*)d_in[1];

    // ws: [partials 8KB][bit image @16KB, 1MB]
    float* partial = (float*)d_ws;
    u64* bits = (u64*)((char*)d_ws + (16 << 10));

    hipLaunchKernelGGL(ls_pack, dim3(4096), dim3(256), 0, stream, tgt, bits);
    hipLaunchKernelGGL(ls_loss, dim3(16, 16, 8), dim3(256), 0, stream, x, bits, partial);
    hipLaunchKernelGGL(ls_final, dim3(1), dim3(1024), 0, stream, partial, (float*)d_out);
}